// Round 3
// baseline (11228.576 us; speedup 1.0000x reference)
//
#include <hip/hip_runtime.h>

// ---------------------------------------------------------------------------
// Stacked BiLSTM autoencoder, fp32.  B=512, T=256, F=64, N=128.
//
// v2: wave-k-split LSTM step. Round-2 rocprof showed the v1 kernel was LDS
// return-bandwidth bound (every thread broadcast-read the whole [x;h] vector:
// 3.1 MB/step/CU delivered -> ~24.6K cyc/step, matching the measured 3.5 ms
// per big stage). Now each of the 8 waves reads only its K/8 slice of v
// (393 KB/step/CU), accumulates partial gate pre-activations for ALL
// (batch,col) in 64 registers/lane, and partials are reduced across waves
// via a 32 KB LDS slab in 4 unit-chunks (fits the 64 KB static-LDS limit).
//   - weights: float4 loads, streamed from L2 each step (time-invariant,
//     786 KB/stage/direction; machine-wide L2 demand ~3.5K cyc/step < VALU)
//   - bias (+ x@W for the time-broadcast d1 stage) pre-reduced into
//     per-gate-thread registers prc[][] before the time loop
//   - gate phase: 256 threads, one (batch,unit) each per chunk; c/h state in
//     registers; h written back to LDS v for the next step.
// Expected: VALU-issue bound at ~6K cyc/step on the 128 busy CUs.
// ---------------------------------------------------------------------------

#define THREADS 512
#define NW 8          // waves per block = k-split factor

__device__ __forceinline__ float sigf(float x) { return 1.0f / (1.0f + __expf(-x)); }

template<int IN, int UH, bool BCAST, bool LASTONLY, int BT, int UC>
__global__ __launch_bounds__(THREADS, 1)
void lstm_stage(const float* __restrict__ xin, const int xfd,
                const float* __restrict__ Wf, const float* __restrict__ Uf, const float* __restrict__ bf,
                const float* __restrict__ Wb, const float* __restrict__ Ub, const float* __restrict__ bb,
                float* __restrict__ out, const int T)
{
    constexpr int NCOL = 4 * UH;            // gate columns
    constexpr int M    = NCOL / 256;        // float4 col-chunks per lane (1 or 2)
    constexpr int K    = BCAST ? UH : (IN + UH);   // per-step reduction depth
    constexpr int KS   = K / NW;            // k-slice per wave
    constexpr int VK   = BCAST ? UH : (IN + UH);   // v row length
    constexpr int HOFF = BCAST ? 0 : IN;    // offset of h inside v row
    constexpr int UQ   = UH / UC;           // units per reduce-chunk (32 for all stages)
    constexpr int CCOL = NCOL / UC;         // slab cols per chunk (4*UQ)
    constexpr int GT   = BT * UQ;           // gate threads per chunk (256)
    static_assert(KS % 4 == 0 && IN % 4 == 0, "vec4 k");
    static_assert(NCOL % 256 == 0 && UQ % 4 == 0 && GT <= THREADS, "layout");
    static_assert(!BCAST || (IN / NW) % 4 == 0, "prologue k");

    const int  dir = blockIdx.y;
    const bool rev = (dir != 0);
    const float* __restrict__ W    = dir ? Wb : Wf;
    const float* __restrict__ U    = dir ? Ub : Uf;
    const float* __restrict__ bias = dir ? bb : bf;

    const int b0  = blockIdx.x * BT;
    const int tid = threadIdx.x;
    const int wv  = tid >> 6;
    const int ln  = tid & 63;
    const int k0  = wv * KS;

    __shared__ float v[BT][VK];                 // [x_t ; h] (or h only, BCAST)
    __shared__ float slab[NW][BT][CCOL];        // per-wave partials, one chunk

    const int gb  = tid / UQ;                   // gate thread: batch
    const int gul = tid % UQ;                   //              unit-in-chunk

    // zero h
    for (int i = tid; i < BT * UH; i += THREADS) v[i / UH][HOFF + (i % UH)] = 0.0f;

    // persistent per-thread gate state: cell c, and pre-computed z-offset
    // (bias, plus x@W for BCAST) per chunk/gate.
    float cst[UC];
    float prc[UC][4];
    #pragma unroll
    for (int c = 0; c < UC; ++c) {
        cst[c] = 0.0f;
        #pragma unroll
        for (int g = 0; g < 4; ++g) prc[c][g] = 0.0f;
    }
    if (tid < GT) {
        #pragma unroll
        for (int c = 0; c < UC; ++c) {
            const int u = c * UQ + gul;
            #pragma unroll
            for (int g = 0; g < 4; ++g) prc[c][g] = bias[g * UH + u];
        }
    }

    if (BCAST) {
        // fold x@W (time-constant input) into prc, k-split + chunk-reduced
        constexpr int KS0 = IN / NW;
        float4 a0[BT][M];
        #pragma unroll
        for (int b = 0; b < BT; ++b)
            #pragma unroll
            for (int m = 0; m < M; ++m) a0[b][m] = make_float4(0.f, 0.f, 0.f, 0.f);
        const int kp0 = wv * KS0;
        for (int kb = 0; kb < KS0; kb += 4) {
            const int k = kp0 + kb;
            const float* row = W + (size_t)k * NCOL;
            float4 xv[BT];
            #pragma unroll
            for (int b = 0; b < BT; ++b)
                xv[b] = *(const float4*)&xin[(size_t)(b0 + b) * IN + k];
            #pragma unroll
            for (int r = 0; r < 4; ++r) {
                #pragma unroll
                for (int m = 0; m < M; ++m) {
                    const float4 w4 = *(const float4*)&row[(size_t)r * NCOL + 4 * ln + 256 * m];
                    #pragma unroll
                    for (int b = 0; b < BT; ++b) {
                        const float s = (r == 0) ? xv[b].x : (r == 1) ? xv[b].y : (r == 2) ? xv[b].z : xv[b].w;
                        a0[b][m].x = fmaf(s, w4.x, a0[b][m].x);
                        a0[b][m].y = fmaf(s, w4.y, a0[b][m].y);
                        a0[b][m].z = fmaf(s, w4.z, a0[b][m].z);
                        a0[b][m].w = fmaf(s, w4.w, a0[b][m].w);
                    }
                }
            }
        }
        #pragma unroll
        for (int c = 0; c < UC; ++c) {
            #pragma unroll
            for (int m = 0; m < M; ++m) {
                const int col4 = 4 * ln + 256 * m, g = col4 / UH, u0 = col4 % UH;
                if (u0 / UQ == c) {
                    const int cl = g * UQ + (u0 - c * UQ);
                    #pragma unroll
                    for (int b = 0; b < BT; ++b) *(float4*)&slab[wv][b][cl] = a0[b][m];
                }
            }
            __syncthreads();
            if (tid < GT) {
                #pragma unroll
                for (int g = 0; g < 4; ++g) {
                    float s = 0.0f;
                    #pragma unroll
                    for (int w = 0; w < NW; ++w) s += slab[w][gb][g * UQ + gul];
                    prc[c][g] += s;
                }
            }
            __syncthreads();
        }
    }

    for (int p = 0; p < T; ++p) {
        const int t = rev ? (T - 1 - p) : p;

        if (!BCAST) {
            // stage x_t (disjoint from h region and slab)
            for (int q4 = tid * 4; q4 < BT * IN; q4 += THREADS * 4) {
                const int b = q4 / IN, f = q4 % IN;
                *(float4*)&v[b][f] =
                    *(const float4*)&xin[((size_t)(b0 + b) * T + t) * xfd + f];
            }
        }
        __syncthreads();   // A: v complete (x staged, h from prev step);
                           //    prev-step slab reads all done

        // GEMM over this wave's k-slice: partials for ALL (b,col) in regs
        float4 acc[BT][M];
        #pragma unroll
        for (int b = 0; b < BT; ++b)
            #pragma unroll
            for (int m = 0; m < M; ++m) acc[b][m] = make_float4(0.f, 0.f, 0.f, 0.f);

        for (int kb = 0; kb < KS; kb += 4) {
            const int k = k0 + kb;
            const float* row;
            if (BCAST) row = U + (size_t)k * NCOL;
            else       row = (k < IN) ? (W + (size_t)k * NCOL)
                                      : (U + (size_t)(k - IN) * NCOL);
            float4 vb[BT];
            #pragma unroll
            for (int b = 0; b < BT; ++b) vb[b] = *(const float4*)&v[b][k];  // broadcast
            #pragma unroll
            for (int r = 0; r < 4; ++r) {
                #pragma unroll
                for (int m = 0; m < M; ++m) {
                    const float4 w4 = *(const float4*)&row[(size_t)r * NCOL + 4 * ln + 256 * m];
                    #pragma unroll
                    for (int b = 0; b < BT; ++b) {
                        const float s = (r == 0) ? vb[b].x : (r == 1) ? vb[b].y : (r == 2) ? vb[b].z : vb[b].w;
                        acc[b][m].x = fmaf(s, w4.x, acc[b][m].x);
                        acc[b][m].y = fmaf(s, w4.y, acc[b][m].y);
                        acc[b][m].z = fmaf(s, w4.z, acc[b][m].z);
                        acc[b][m].w = fmaf(s, w4.w, acc[b][m].w);
                    }
                }
            }
        }

        // chunked cross-wave reduce + gate phase (slab reused per chunk)
        #pragma unroll
        for (int c = 0; c < UC; ++c) {
            #pragma unroll
            for (int m = 0; m < M; ++m) {
                const int col4 = 4 * ln + 256 * m, g = col4 / UH, u0 = col4 % UH;
                if (u0 / UQ == c) {
                    const int cl = g * UQ + (u0 - c * UQ);
                    #pragma unroll
                    for (int b = 0; b < BT; ++b) *(float4*)&slab[wv][b][cl] = acc[b][m];
                }
            }
            __syncthreads();   // B_c: chunk partials visible
            if (tid < GT) {
                const int u = c * UQ + gul;
                float z0 = prc[c][0], z1 = prc[c][1], z2 = prc[c][2], z3 = prc[c][3];
                #pragma unroll
                for (int w = 0; w < NW; ++w) {
                    z0 += slab[w][gb][0 * UQ + gul];
                    z1 += slab[w][gb][1 * UQ + gul];
                    z2 += slab[w][gb][2 * UQ + gul];
                    z3 += slab[w][gb][3 * UQ + gul];
                }
                const float iv = sigf(z0);
                const float fv = sigf(z1);
                const float gv = fmaxf(z2, 0.0f);
                const float ov = sigf(z3);
                const float cc = fv * cst[c] + iv * gv;
                cst[c] = cc;
                const float h = ov * fmaxf(cc, 0.0f);
                v[gb][HOFF + u] = h;               // next step's recurrent input
                if (!LASTONLY) {
                    out[((size_t)(b0 + gb) * T + t) * (2 * UH) + (size_t)dir * UH + u] = h;
                } else if (p == T - 1) {
                    out[(size_t)(b0 + gb) * (2 * UH) + (size_t)dir * UH + u] = h;
                }
            }
            if (c < UC - 1) __syncthreads();  // C_c: slab reads done before next
                                              // chunk overwrites (last chunk: A)
        }
    }
}

// out(rows,64) = h(rows,256) @ Wd(256,64) + bd
__global__ __launch_bounds__(256, 1)
void dense_out(const float* __restrict__ h, const float* __restrict__ Wd,
               const float* __restrict__ bd, float* __restrict__ out, const int rows)
{
    const int tid = threadIdx.x;
    const int lc  = (tid & 15) * 4;
    const size_t row = (size_t)blockIdx.x * 16 + (tid >> 4);
    if (row >= (size_t)rows) return;
    const float* hr = h + row * 256;
    float4 a;
    a.x = bd[lc]; a.y = bd[lc + 1]; a.z = bd[lc + 2]; a.w = bd[lc + 3];
    #pragma unroll 4
    for (int k = 0; k < 256; k += 4) {
        const float4 hv = *reinterpret_cast<const float4*>(&hr[k]);
        const float4 w0 = *reinterpret_cast<const float4*>(&Wd[(size_t)(k + 0) * 64 + lc]);
        const float4 w1 = *reinterpret_cast<const float4*>(&Wd[(size_t)(k + 1) * 64 + lc]);
        const float4 w2 = *reinterpret_cast<const float4*>(&Wd[(size_t)(k + 2) * 64 + lc]);
        const float4 w3 = *reinterpret_cast<const float4*>(&Wd[(size_t)(k + 3) * 64 + lc]);
        a.x = fmaf(hv.x, w0.x, a.x); a.y = fmaf(hv.x, w0.y, a.y); a.z = fmaf(hv.x, w0.z, a.z); a.w = fmaf(hv.x, w0.w, a.w);
        a.x = fmaf(hv.y, w1.x, a.x); a.y = fmaf(hv.y, w1.y, a.y); a.z = fmaf(hv.y, w1.z, a.z); a.w = fmaf(hv.y, w1.w, a.w);
        a.x = fmaf(hv.z, w2.x, a.x); a.y = fmaf(hv.z, w2.y, a.y); a.z = fmaf(hv.z, w2.z, a.z); a.w = fmaf(hv.z, w2.w, a.w);
        a.x = fmaf(hv.w, w3.x, a.x); a.y = fmaf(hv.w, w3.y, a.y); a.z = fmaf(hv.w, w3.z, a.z); a.w = fmaf(hv.w, w3.w, a.w);
    }
    *reinterpret_cast<float4*>(&out[row * 64 + lc]) = a;
}

extern "C" void kernel_launch(void* const* d_in, const int* in_sizes, int n_in,
                              void* d_out, int out_size, void* d_ws, size_t ws_size,
                              hipStream_t stream)
{
    (void)in_sizes; (void)n_in; (void)out_size;
    constexpr int B = 512, T = 256;
    constexpr int BT = 8;

    const size_t n_h1 = (size_t)B * T * 256;
    const size_t n_h2 = (size_t)B * T * 128;
    const size_t n_zv = (size_t)B * 128;
    const size_t need_bytes = (n_h1 + n_h2 + n_zv) * sizeof(float);  // ~192.2 MiB
    if (ws_size < need_bytes) return;   // clean failure instead of OOB crash

    const float* x    = (const float*)d_in[0];
    const float* e1fW = (const float*)d_in[1];
    const float* e1fU = (const float*)d_in[2];
    const float* e1fb = (const float*)d_in[3];
    const float* e1bW = (const float*)d_in[4];
    const float* e1bU = (const float*)d_in[5];
    const float* e1bb = (const float*)d_in[6];
    const float* e2fW = (const float*)d_in[7];
    const float* e2fU = (const float*)d_in[8];
    const float* e2fb = (const float*)d_in[9];
    const float* e2bW = (const float*)d_in[10];
    const float* e2bU = (const float*)d_in[11];
    const float* e2bb = (const float*)d_in[12];
    const float* d1fW = (const float*)d_in[13];
    const float* d1fU = (const float*)d_in[14];
    const float* d1fb = (const float*)d_in[15];
    const float* d1bW = (const float*)d_in[16];
    const float* d1bU = (const float*)d_in[17];
    const float* d1bb = (const float*)d_in[18];
    const float* d2fW = (const float*)d_in[19];
    const float* d2fU = (const float*)d_in[20];
    const float* d2fb = (const float*)d_in[21];
    const float* d2bW = (const float*)d_in[22];
    const float* d2bU = (const float*)d_in[23];
    const float* d2bb = (const float*)d_in[24];
    const float* Wd   = (const float*)d_in[25];
    const float* bd   = (const float*)d_in[26];
    float* out = (float*)d_out;

    float* ws = (float*)d_ws;
    float* h1 = ws;
    float* h2 = ws + n_h1;
    float* zv = h2 + n_h2;
    float* h3 = h1;                               // reuse (h1 dead after e2)

    const dim3 grid(B / BT, 2), blk(THREADS);

    // e1: in=64, u=128 -> h1 (B,T,256)
    lstm_stage<64, 128, false, false, BT, 4><<<grid, blk, 0, stream>>>(
        x, 64, e1fW, e1fU, e1fb, e1bW, e1bU, e1bb, h1, T);
    // e2: in=256, u=64, final state only -> zv (B,128)
    lstm_stage<256, 64, false, true, BT, 2><<<grid, blk, 0, stream>>>(
        h1, 256, e2fW, e2fU, e2fb, e2bW, e2bU, e2bb, zv, T);
    // d1: in=128 (time-broadcast z), u=64 -> h2 (B,T,128)
    lstm_stage<128, 64, true, false, BT, 2><<<grid, blk, 0, stream>>>(
        zv, 128, d1fW, d1fU, d1fb, d1bW, d1bU, d1bb, h2, T);
    // d2: in=128, u=128 -> h3 (B,T,256)
    lstm_stage<128, 128, false, false, BT, 4><<<grid, blk, 0, stream>>>(
        h2, 128, d2fW, d2fU, d2fb, d2bW, d2bU, d2bb, h3, T);
    // dense head
    dense_out<<<(B * T + 15) / 16, 256, 0, stream>>>(h3, Wd, bd, out, B * T);
}

// Round 4
// 3132.301 us; speedup vs baseline: 3.5848x; 3.5848x over previous
//
#include <hip/hip_runtime.h>

// ---------------------------------------------------------------------------
// Stacked BiLSTM autoencoder, fp32.  B=512, T=256, F=64, N=128.
//
// v3: register-resident recurrent weights + hoisted input GEMMs.
// Round-3 evidence: streaming weights from L2 per step collapsed (6.3 GB HBM
// fetch/dispatch, VALUBusy 6.9%). Round-2 evidence: 128 blocks leave half the
// machine idle. Fixes:
//   - BT=4 -> 256 blocks (1/CU), 512 threads, 2 waves/SIMD.
//   - U (and e1's small W) held in VGPRs for all 256 steps: the recurrence
//     does ZERO per-step global weight reads.
//   - e2/d2 input GEMM xz = x@W hoisted out (reference does this too),
//     computed by a tiled fp32 GEMM in T-chunks (TC in {64,32,16} picked from
//     ws_size); recurrence reads xz_t streamed (prefetched into regs).
//   - d1: z is time-constant -> z@W folded into per-gate-thread prologue.
//   - per step: KH=4 k-split reg-GEMM -> LDS slab -> gate; 2 barriers.
// ---------------------------------------------------------------------------

#define THREADS 512

__device__ __forceinline__ float sigf(float x) { return 1.0f / (1.0f + __expf(-x)); }

// MODE: 0 = e1 (x direct, IN=64, W in regs), 1 = xz-fed (e2/d2), 2 = d1 (z bcast prologue, ZDIM=128)
template<int UH, int CT, int KH, int MODE, bool LASTONLY, int BT>
__global__ __launch_bounds__(THREADS, 2)
void lstm_rec(const float* __restrict__ xin,          // M0: x (B,T,64); M1: xz [2][TC][B][NCOL]; M2: z (B,128)
              const float* __restrict__ Uf, const float* __restrict__ Ub,
              const float* __restrict__ bf, const float* __restrict__ bb,
              const float* __restrict__ Wf, const float* __restrict__ Wb,  // M0/M2 only
              float* __restrict__ out,
              float* __restrict__ stc, float* __restrict__ sth,            // state [2][B][UH]
              const int T, const int t0, const int TC, const int FIRST, const int LASTC)
{
    constexpr int NCOL = 4 * UH;
    constexpr int CG   = NCOL / CT;          // column groups (must be 128)
    constexpr int URPK = UH / KH;            // U rows per k-slice
    constexpr int IN   = (MODE == 0) ? 64 : ((MODE == 2) ? 128 : 4);
    constexpr int XRPK = (MODE == 0) ? (IN / KH) : 4;
    constexpr int GT   = BT * UH;            // gate threads
    static_assert(CG == 128 && CG * KH == THREADS, "mapping");
    static_assert(URPK % 4 == 0 && (MODE != 0 || XRPK % 4 == 0), "vec4");
    static_assert(GT <= THREADS, "gate");

    const int dir = blockIdx.y;
    const bool rev = (dir != 0);
    const float* __restrict__ U    = dir ? Ub : Uf;
    const float* __restrict__ Wm   = dir ? Wb : Wf;
    const float* __restrict__ bias = dir ? bb : bf;

    const int b0  = blockIdx.x * BT;
    const int tid = threadIdx.x;
    const int kh  = tid >> 7;                // k-slice (wave-uniform: CG=128)
    const int cg  = tid & 127;               // column within group

    __shared__ float v[BT][UH];              // h
    __shared__ float slab[KH][BT][NCOL];     // partial gate pre-activations
    __shared__ float xb[BT][IN];             // e1: x_t ; d1: z ; M1: unused(4)

    // ---- load recurrent weights into registers (held for all T steps) ----
    float wu[CT][URPK];
    #pragma unroll
    for (int j = 0; j < CT; ++j)
        #pragma unroll
        for (int r = 0; r < URPK; ++r)
            wu[j][r] = U[(size_t)(kh * URPK + r) * NCOL + cg + j * CG];

    float wx[CT][XRPK];
    if (MODE == 0) {
        #pragma unroll
        for (int j = 0; j < CT; ++j)
            #pragma unroll
            for (int r = 0; r < XRPK; ++r)
                wx[j][r] = Wm[(size_t)(kh * XRPK + r) * NCOL + cg + j * CG];
    }

    const int gb = tid / UH;                 // gate thread's batch
    const int gu = tid % UH;                 //               unit

    // ---- init state ----
    float cst = 0.0f, prc[4];
    if (FIRST) {
        for (int i = tid; i < BT * UH; i += THREADS) v[i / UH][i % UH] = 0.0f;
    } else if (tid < GT) {
        cst = stc[((size_t)dir * 512 + b0 + gb) * UH + gu];
        v[gb][gu] = sth[((size_t)dir * 512 + b0 + gb) * UH + gu];
    }
    if (tid < GT) {
        #pragma unroll
        for (int g = 0; g < 4; ++g) prc[g] = bias[g * UH + gu];
    }

    if (MODE == 2) {
        // stage z and fold z@W into prc (once)
        {
            const int b = tid / IN, k = tid % IN;           // BT*IN == THREADS
            xb[b][k] = xin[(size_t)(b0 + b) * IN + k];
        }
        __syncthreads();
        if (tid < GT) {
            for (int k = 0; k < IN; ++k) {
                const float zk = xb[gb][k];
                #pragma unroll
                for (int g = 0; g < 4; ++g)
                    prc[g] = fmaf(zk, Wm[(size_t)k * NCOL + g * UH + gu], prc[g]);
            }
        }
    }

    float hlast = 0.0f;

    for (int p = 0; p < TC; ++p) {
        const int gt = rev ? (T - 1 - (t0 + p)) : (t0 + p);

        float xzp[4];
        if (MODE == 0) {
            if (tid < 64) {                                  // stage x_t (BT*64 floats)
                const int b = tid >> 4, f = (tid & 15) * 4;
                *(float4*)&xb[b][f] =
                    *(const float4*)&xin[((size_t)(b0 + b) * T + gt) * 64 + f];
            }
        } else if (MODE == 1) {
            if (tid < GT) {                                  // prefetch xz_t (hidden under GEMM)
                const float* xr = xin + (((size_t)dir * TC + p) * 512 + (b0 + gb)) * NCOL;
                #pragma unroll
                for (int g = 0; g < 4; ++g) xzp[g] = xr[g * UH + gu];
            }
        }
        __syncthreads();   // A: h (and x) ready; prev slab reads done

        // ---- reg-resident GEMM over this thread's k-slice ----
        float acc[CT][BT];
        #pragma unroll
        for (int j = 0; j < CT; ++j)
            #pragma unroll
            for (int b = 0; b < BT; ++b) acc[j][b] = 0.0f;

        if (MODE == 0) {
            #pragma unroll
            for (int r = 0; r < XRPK; r += 4) {
                float4 xv[BT];
                #pragma unroll
                for (int b = 0; b < BT; ++b)
                    xv[b] = *(const float4*)&xb[b][kh * XRPK + r];
                #pragma unroll
                for (int j = 0; j < CT; ++j)
                    #pragma unroll
                    for (int b = 0; b < BT; ++b) {
                        acc[j][b] = fmaf(xv[b].x, wx[j][r + 0], acc[j][b]);
                        acc[j][b] = fmaf(xv[b].y, wx[j][r + 1], acc[j][b]);
                        acc[j][b] = fmaf(xv[b].z, wx[j][r + 2], acc[j][b]);
                        acc[j][b] = fmaf(xv[b].w, wx[j][r + 3], acc[j][b]);
                    }
            }
        }
        #pragma unroll
        for (int r = 0; r < URPK; r += 4) {
            float4 hv[BT];
            #pragma unroll
            for (int b = 0; b < BT; ++b)
                hv[b] = *(const float4*)&v[b][kh * URPK + r];
            #pragma unroll
            for (int j = 0; j < CT; ++j)
                #pragma unroll
                for (int b = 0; b < BT; ++b) {
                    acc[j][b] = fmaf(hv[b].x, wu[j][r + 0], acc[j][b]);
                    acc[j][b] = fmaf(hv[b].y, wu[j][r + 1], acc[j][b]);
                    acc[j][b] = fmaf(hv[b].z, wu[j][r + 2], acc[j][b]);
                    acc[j][b] = fmaf(hv[b].w, wu[j][r + 3], acc[j][b]);
                }
        }
        #pragma unroll
        for (int j = 0; j < CT; ++j)
            #pragma unroll
            for (int b = 0; b < BT; ++b) slab[kh][b][cg + j * CG] = acc[j][b];

        __syncthreads();   // B: slab complete

        if (tid < GT) {
            float z[4];
            #pragma unroll
            for (int g = 0; g < 4; ++g) {
                z[g] = prc[g];
                if (MODE == 1) z[g] += xzp[g];
                #pragma unroll
                for (int w = 0; w < KH; ++w) z[g] += slab[w][gb][g * UH + gu];
            }
            const float iv = sigf(z[0]);
            const float fv = sigf(z[1]);
            const float gv = fmaxf(z[2], 0.0f);
            const float ov = sigf(z[3]);
            const float c  = fv * cst + iv * gv;
            cst = c;
            const float h = ov * fmaxf(c, 0.0f);
            hlast = h;
            v[gb][gu] = h;
            if (!LASTONLY) {
                out[((size_t)(b0 + gb) * T + gt) * (2 * UH) + (size_t)dir * UH + gu] = h;
            } else if (LASTC && p == TC - 1) {
                out[(size_t)(b0 + gb) * (2 * UH) + (size_t)dir * UH + gu] = h;
            }
        }
        // top-of-loop barrier A orders h/x/slab for the next step
    }

    if (tid < GT) {       // carry state across chunks (harmless when LASTC)
        stc[((size_t)dir * 512 + b0 + gb) * UH + gu] = cst;
        sth[((size_t)dir * 512 + b0 + gb) * UH + gu] = hlast;
    }
}

// xz[dir][lt][b][col] = A[b][g_t(dir,lt)][:] @ W_dir[:,col]   (64x64 tile, 4x4 micro)
template<int K, int NCOL>
__global__ __launch_bounds__(256, 2)
void xz_gemm(const float* __restrict__ A,              // (B=512, T, K)
             const float* __restrict__ Wf, const float* __restrict__ Wb,
             float* __restrict__ xz, const int T, const int t0, const int TC)
{
    const int dir = blockIdx.z;
    const float* __restrict__ W = dir ? Wb : Wf;
    const int row0 = blockIdx.x * 64;                  // row id = lt*512 + b
    const int col0 = blockIdx.y * 64;
    const int tid = threadIdx.x;
    const int tx = tid & 15, ty = tid >> 4;

    __shared__ float As[64][17];
    __shared__ float Bs[16][64];

    float acc[4][4];
    #pragma unroll
    for (int i = 0; i < 4; ++i)
        #pragma unroll
        for (int j = 0; j < 4; ++j) acc[i][j] = 0.0f;

    const int r_st  = tid >> 2;                        // A-stage: row within tile
    const int kq    = (tid & 3) * 4;                   //          k within chunk
    const int rowA  = row0 + r_st;
    const int ltA   = rowA >> 9, bA = rowA & 511;
    const int gtA   = dir ? (T - 1 - (t0 + ltA)) : (t0 + ltA);
    const float* Arow = A + ((size_t)bA * T + gtA) * K;
    const int kr = tid >> 4, c4 = (tid & 15) * 4;      // B-stage

    for (int kc = 0; kc < K; kc += 16) {
        *(float4*)&As[r_st][kq] = *(const float4*)&Arow[kc + kq];
        *(float4*)&Bs[kr][c4]   = *(const float4*)&W[(size_t)(kc + kr) * NCOL + col0 + c4];
        __syncthreads();
        #pragma unroll
        for (int kk = 0; kk < 16; ++kk) {
            float a[4];
            #pragma unroll
            for (int i = 0; i < 4; ++i) a[i] = As[ty * 4 + i][kk];
            const float4 bv = *(const float4*)&Bs[kk][tx * 4];
            #pragma unroll
            for (int i = 0; i < 4; ++i) {
                acc[i][0] = fmaf(a[i], bv.x, acc[i][0]);
                acc[i][1] = fmaf(a[i], bv.y, acc[i][1]);
                acc[i][2] = fmaf(a[i], bv.z, acc[i][2]);
                acc[i][3] = fmaf(a[i], bv.w, acc[i][3]);
            }
        }
        __syncthreads();
    }
    #pragma unroll
    for (int i = 0; i < 4; ++i) {
        const int row = row0 + ty * 4 + i;
        const int lt = row >> 9, b = row & 511;
        float4 o; o.x = acc[i][0]; o.y = acc[i][1]; o.z = acc[i][2]; o.w = acc[i][3];
        *(float4*)&xz[(((size_t)dir * TC + lt) * 512 + b) * NCOL + col0 + tx * 4] = o;
    }
}

// out(rows,64) = h(rows,256) @ Wd(256,64) + bd
__global__ __launch_bounds__(256, 1)
void dense_out(const float* __restrict__ h, const float* __restrict__ Wd,
               const float* __restrict__ bd, float* __restrict__ out, const int rows)
{
    const int tid = threadIdx.x;
    const int lc  = (tid & 15) * 4;
    const size_t row = (size_t)blockIdx.x * 16 + (tid >> 4);
    if (row >= (size_t)rows) return;
    const float* hr = h + row * 256;
    float4 a;
    a.x = bd[lc]; a.y = bd[lc + 1]; a.z = bd[lc + 2]; a.w = bd[lc + 3];
    #pragma unroll 4
    for (int k = 0; k < 256; k += 4) {
        const float4 hv = *reinterpret_cast<const float4*>(&hr[k]);
        const float4 w0 = *reinterpret_cast<const float4*>(&Wd[(size_t)(k + 0) * 64 + lc]);
        const float4 w1 = *reinterpret_cast<const float4*>(&Wd[(size_t)(k + 1) * 64 + lc]);
        const float4 w2 = *reinterpret_cast<const float4*>(&Wd[(size_t)(k + 2) * 64 + lc]);
        const float4 w3 = *reinterpret_cast<const float4*>(&Wd[(size_t)(k + 3) * 64 + lc]);
        a.x = fmaf(hv.x, w0.x, a.x); a.y = fmaf(hv.x, w0.y, a.y); a.z = fmaf(hv.x, w0.z, a.z); a.w = fmaf(hv.x, w0.w, a.w);
        a.x = fmaf(hv.y, w1.x, a.x); a.y = fmaf(hv.y, w1.y, a.y); a.z = fmaf(hv.y, w1.z, a.z); a.w = fmaf(hv.y, w1.w, a.w);
        a.x = fmaf(hv.z, w2.x, a.x); a.y = fmaf(hv.z, w2.y, a.y); a.z = fmaf(hv.z, w2.z, a.z); a.w = fmaf(hv.z, w2.w, a.w);
        a.x = fmaf(hv.w, w3.x, a.x); a.y = fmaf(hv.w, w3.y, a.y); a.z = fmaf(hv.w, w3.z, a.z); a.w = fmaf(hv.w, w3.w, a.w);
    }
    *reinterpret_cast<float4*>(&out[row * 64 + lc]) = a;
}

extern "C" void kernel_launch(void* const* d_in, const int* in_sizes, int n_in,
                              void* d_out, int out_size, void* d_ws, size_t ws_size,
                              hipStream_t stream)
{
    (void)in_sizes; (void)n_in; (void)out_size;
    constexpr int B = 512, T = 256, BT = 4;

    // workspace (floats)
    const size_t n_h1 = (size_t)B * T * 256;          // 33,554,432
    const size_t n_h2 = (size_t)B * T * 128;          // 16,777,216
    const size_t n_z  = (size_t)B * 128;              //     65,536
    const size_t n_st = 2 * ((size_t)2 * B * 64) + 2 * ((size_t)2 * B * 128); // 393,216
    const size_t base = n_h1 + n_h2 + n_z + n_st;
    int TC = 0;
    for (int tc : {64, 32, 16}) {
        if ((base + (size_t)tc * 2 * B * 512) * sizeof(float) <= ws_size) { TC = tc; break; }
    }
    if (!TC) return;                                   // clean fail, no OOB
    const int NCH = T / TC;

    const float* x    = (const float*)d_in[0];
    const float* e1fW = (const float*)d_in[1];
    const float* e1fU = (const float*)d_in[2];
    const float* e1fb = (const float*)d_in[3];
    const float* e1bW = (const float*)d_in[4];
    const float* e1bU = (const float*)d_in[5];
    const float* e1bb = (const float*)d_in[6];
    const float* e2fW = (const float*)d_in[7];
    const float* e2fU = (const float*)d_in[8];
    const float* e2fb = (const float*)d_in[9];
    const float* e2bW = (const float*)d_in[10];
    const float* e2bU = (const float*)d_in[11];
    const float* e2bb = (const float*)d_in[12];
    const float* d1fW = (const float*)d_in[13];
    const float* d1fU = (const float*)d_in[14];
    const float* d1fb = (const float*)d_in[15];
    const float* d1bW = (const float*)d_in[16];
    const float* d1bU = (const float*)d_in[17];
    const float* d1bb = (const float*)d_in[18];
    const float* d2fW = (const float*)d_in[19];
    const float* d2fU = (const float*)d_in[20];
    const float* d2fb = (const float*)d_in[21];
    const float* d2bW = (const float*)d_in[22];
    const float* d2bU = (const float*)d_in[23];
    const float* d2bb = (const float*)d_in[24];
    const float* Wd   = (const float*)d_in[25];
    const float* bd   = (const float*)d_in[26];
    float* out = (float*)d_out;

    float* ws   = (float*)d_ws;
    float* h1   = ws;                     // also h3 (h1 dead after e2)
    float* h2   = h1 + n_h1;
    float* zv   = h2 + n_h2;
    float* st   = zv + n_z;
    float* stcE = st;                     // e2 c  [2][B][64]
    float* sthE = stcE + (size_t)2 * B * 64;
    float* stcD = sthE + (size_t)2 * B * 64;   // d2 c [2][B][128]
    float* sthD = stcD + (size_t)2 * B * 128;
    float* xzb  = st + n_st;
    float* h3   = h1;

    const dim3 rgrid(B / BT, 2), rblk(THREADS);

    // e1: W+U in regs, x direct, full T
    lstm_rec<128, 4, 4, 0, false, BT><<<rgrid, rblk, 0, stream>>>(
        x, e1fU, e1bU, e1fb, e1bb, e1fW, e1bW, h1, stcD, sthD, T, 0, T, 1, 1);

    // e2: xz chunks + chunked recurrence (LASTONLY -> zv)
    for (int c = 0; c < NCH; ++c) {
        xz_gemm<256, 256><<<dim3(TC * B / 64, 256 / 64, 2), 256, 0, stream>>>(
            h1, e2fW, e2bW, xzb, T, c * TC, TC);
        lstm_rec<64, 2, 4, 1, true, BT><<<rgrid, rblk, 0, stream>>>(
            xzb, e2fU, e2bU, e2fb, e2bb, nullptr, nullptr, zv, stcE, sthE,
            T, c * TC, TC, c == 0, c == NCH - 1);
    }

    // d1: z bcast prologue, U in regs, full T
    lstm_rec<64, 2, 4, 2, false, BT><<<rgrid, rblk, 0, stream>>>(
        zv, d1fU, d1bU, d1fb, d1bb, d1fW, d1bW, h2, stcE, sthE, T, 0, T, 1, 1);

    // d2: xz chunks + chunked recurrence -> h3
    for (int c = 0; c < NCH; ++c) {
        xz_gemm<128, 512><<<dim3(TC * B / 64, 512 / 64, 2), 256, 0, stream>>>(
            h2, d2fW, d2bW, xzb, T, c * TC, TC);
        lstm_rec<128, 4, 4, 1, false, BT><<<rgrid, rblk, 0, stream>>>(
            xzb, d2fU, d2bU, d2fb, d2bb, nullptr, nullptr, h3, stcD, sthD,
            T, c * TC, TC, c == 0, c == NCH - 1);
    }

    dense_out<<<(B * T + 15) / 16, 256, 0, stream>>>(h3, Wd, bd, out, B * T);
}